// Round 1
// baseline (179.479 us; speedup 1.0000x reference)
//
#include <hip/hip_runtime.h>

#define B_DIM 8192
#define NIN   1024
#define NOUT  1024
#define KDIM  2048

#define BM 128
#define BN 64
#define BK 64

typedef __bf16 bf16x8 __attribute__((ext_vector_type(8)));
typedef float  f32x4  __attribute__((ext_vector_type(4)));

__device__ __forceinline__ unsigned short f2bf(float f) {
  unsigned int u = __float_as_uint(f);
  u += 0x7fff + ((u >> 16) & 1);   // round-to-nearest-even
  return (unsigned short)(u >> 16);
}

__device__ __forceinline__ float sigmoid_f(float x) {
  return 1.0f / (1.0f + __expf(-x));
}
__device__ __forceinline__ float tanh_f(float x) {
  return 1.0f - 2.0f / (__expf(2.0f * x) + 1.0f);
}

__device__ __forceinline__ void gload_lds16(const void* g, void* l) {
  __builtin_amdgcn_global_load_lds(
      (const __attribute__((address_space(1))) void*)g,
      (__attribute__((address_space(3))) void*)l, 16, 0, 0);
}

// ---------------- kernel 1: pack xh = concat(x, out_tm1) as bf16 ------------
__global__ void pack_xh_kernel(const float* __restrict__ x,
                               const float* __restrict__ h,
                               unsigned short* __restrict__ xh) {
  const long total = (long)B_DIM * KDIM / 4;
  for (long i = (long)blockIdx.x * blockDim.x + threadIdx.x; i < total;
       i += (long)gridDim.x * blockDim.x) {
    long e = i * 4;
    int b = (int)(e >> 11);
    int c = (int)(e & 2047);
    float4 v = (c < NIN)
        ? *reinterpret_cast<const float4*>(x + (long)b * NIN + c)
        : *reinterpret_cast<const float4*>(h + (long)b * NOUT + (c - NIN));
    ushort4 o;
    o.x = f2bf(v.x); o.y = f2bf(v.y); o.z = f2bf(v.z); o.w = f2bf(v.w);
    *reinterpret_cast<ushort4*>(xh + e) = o;
  }
}

// ------------- kernel 2: WT[g][n][k] = bf16(W_g[k][n])  (transpose) ---------
__global__ void transpose_w_kernel(const float* __restrict__ Wf,
                                   const float* __restrict__ Wi,
                                   const float* __restrict__ Wc,
                                   const float* __restrict__ Wo,
                                   unsigned short* __restrict__ wt) {
  __shared__ float tile[32][33];
  const int g = blockIdx.z;
  const float* W = (g == 0) ? Wf : (g == 1) ? Wi : (g == 2) ? Wc : Wo;
  const int n0 = blockIdx.x * 32;
  const int k0 = blockIdx.y * 32;
  const int tx = threadIdx.x, ty = threadIdx.y;
#pragma unroll
  for (int r = ty; r < 32; r += 8)
    tile[r][tx] = W[(long)(k0 + r) * NOUT + n0 + tx];
  __syncthreads();
  unsigned short* dst = wt + (long)g * NOUT * KDIM;
#pragma unroll
  for (int r = ty; r < 32; r += 8)
    dst[(long)(n0 + r) * KDIM + k0 + tx] = f2bf(tile[tx][r]);
}

// ------------- kernel 3: fused 4-gate GEMM + LSTM epilogue ------------------
// xh: [8192][2048] bf16 (row-major, k contiguous)
// wt: [4][1024][2048] bf16 (gate, n, k) -> B fragment = contiguous k per n
__global__ __launch_bounds__(256, 2)
void lstm_gemm_kernel(const unsigned short* __restrict__ xh,
                      const unsigned short* __restrict__ wt,
                      const float* __restrict__ state,
                      const float* __restrict__ bfp,
                      const float* __restrict__ bip,
                      const float* __restrict__ bcp,
                      const float* __restrict__ bop,
                      float* __restrict__ out) {
  __shared__ __attribute__((aligned(16))) unsigned short lds_a[BM * BK];
  __shared__ __attribute__((aligned(16))) unsigned short lds_b[4][BN * BK];

  const int tid  = threadIdx.x;
  const int wave = tid >> 6;
  const int lane = tid & 63;
  const int m0 = blockIdx.y * BM;
  const int n0 = blockIdx.x * BN;
  const int wm = wave >> 1;   // 0..1 : which 64-row half
  const int wn = wave & 1;    // 0..1 : which 32-col half

  f32x4 acc[4][2][4];   // [m-frag][n-frag][gate]
#pragma unroll
  for (int mi = 0; mi < 4; ++mi)
#pragma unroll
    for (int ni = 0; ni < 2; ++ni)
#pragma unroll
      for (int g = 0; g < 4; ++g)
        acc[mi][ni][g] = (f32x4){0.f, 0.f, 0.f, 0.f};

  const char* xh_b = (const char*)xh;
  const char* wt_b = (const char*)wt;

  for (int kt = 0; kt < KDIM / BK; ++kt) {
    // ---- stage A tile [128][64] : 16 KB = 4 wave-chunks of 1 KB per wave
#pragma unroll
    for (int j = 0; j < 4; ++j) {
      int off  = (wave * 4 + j) * 1024 + lane * 16;  // byte offset in tile
      int row  = off >> 7;                            // 128 B per row
      int colb = off & 127;
      gload_lds16(xh_b + ((long)(m0 + row) * 4096 + kt * 128 + colb),
                  (char*)lds_a + (wave * 4 + j) * 1024);
    }
    // ---- stage B tiles: wave w stages gate w's [64][64] tile (8 KB)
#pragma unroll
    for (int j = 0; j < 8; ++j) {
      int off  = j * 1024 + lane * 16;
      int row  = off >> 7;
      int colb = off & 127;
      gload_lds16(wt_b + ((long)wave * 4194304 +
                          (long)(n0 + row) * 4096 + kt * 128 + colb),
                  (char*)lds_b + wave * 8192 + j * 1024);
    }
    __syncthreads();   // drains vmcnt(0) then barrier

    // ---- compute: 2 k-steps of 32
#pragma unroll
    for (int s = 0; s < 2; ++s) {
      const int kb = s * 32 + (lane >> 4) * 8;
      bf16x8 af[4];
#pragma unroll
      for (int mi = 0; mi < 4; ++mi)
        af[mi] = *reinterpret_cast<const bf16x8*>(
            lds_a + (wm * 64 + mi * 16 + (lane & 15)) * BK + kb);
#pragma unroll
      for (int g = 0; g < 4; ++g) {
#pragma unroll
        for (int ni = 0; ni < 2; ++ni) {
          bf16x8 bfr = *reinterpret_cast<const bf16x8*>(
              lds_b[g] + (wn * 32 + ni * 16 + (lane & 15)) * BK + kb);
#pragma unroll
          for (int mi = 0; mi < 4; ++mi)
            acc[mi][ni][g] = __builtin_amdgcn_mfma_f32_16x16x32_bf16(
                af[mi], bfr, acc[mi][ni][g], 0, 0, 0);
        }
      }
    }
    __syncthreads();   // all waves done reading before next stage overwrites
  }

  // ---- epilogue: C/D layout col = lane&15, row = (lane>>4)*4 + reg
  const int colbase = n0 + wn * 32 + (lane & 15);
  const int rowbase = m0 + wm * 64 + ((lane >> 4) << 2);
#pragma unroll
  for (int ni = 0; ni < 2; ++ni) {
    const int c = colbase + ni * 16;
    const float bfv = bfp[c], biv = bip[c], bcv = bcp[c], bov = bop[c];
#pragma unroll
    for (int mi = 0; mi < 4; ++mi) {
      const int r0 = rowbase + mi * 16;
#pragma unroll
      for (int r = 0; r < 4; ++r) {
        const long row = r0 + r;
        float fg = sigmoid_f(acc[mi][ni][0][r] + bfv);
        float ig = sigmoid_f(acc[mi][ni][1][r] + biv);
        float cg = tanh_f(acc[mi][ni][2][r] + bcv);
        float og = sigmoid_f(acc[mi][ni][3][r] + bov);
        float st = state[row * NOUT + c];
        float ns = st * fg + ig * cg;
        out[row * NOUT + c] = og * tanh_f(ns);                 // output_t
        out[(long)B_DIM * NOUT + row * NOUT + c] = ns;         // new_state
      }
    }
  }
}

extern "C" void kernel_launch(void* const* d_in, const int* in_sizes, int n_in,
                              void* d_out, int out_size, void* d_ws, size_t ws_size,
                              hipStream_t stream) {
  const float* x     = (const float*)d_in[0];
  const float* h     = (const float*)d_in[1];
  const float* state = (const float*)d_in[2];
  const float* Wf    = (const float*)d_in[3];
  const float* bfp   = (const float*)d_in[4];
  const float* Wi    = (const float*)d_in[5];
  const float* bip   = (const float*)d_in[6];
  const float* Wc    = (const float*)d_in[7];
  const float* bcp   = (const float*)d_in[8];
  const float* Wo    = (const float*)d_in[9];
  const float* bop   = (const float*)d_in[10];
  float* out = (float*)d_out;

  unsigned short* xh = (unsigned short*)d_ws;                       // 33.55 MB
  unsigned short* wt = (unsigned short*)((char*)d_ws +
                        (size_t)B_DIM * KDIM * 2);                  // 16.78 MB

  hipLaunchKernelGGL(pack_xh_kernel, dim3(2048), dim3(256), 0, stream,
                     x, h, xh);
  hipLaunchKernelGGL(transpose_w_kernel, dim3(NOUT / 32, KDIM / 32, 4),
                     dim3(32, 8), 0, stream, Wf, Wi, Wc, Wo, wt);
  hipLaunchKernelGGL(lstm_gemm_kernel, dim3(NOUT / BN, B_DIM / BM),
                     dim3(256), 0, stream,
                     xh, wt, state, bfp, bip, bcp, bop, out);
}

// Round 2
// 158.137 us; speedup vs baseline: 1.1350x; 1.1350x over previous
//
#include <hip/hip_runtime.h>

#define B_DIM 8192
#define NOUT  1024
#define KDIM  2048
#define NCI   4096   // 4 gates x 1024, interleaved

typedef __bf16 bf16x8 __attribute__((ext_vector_type(8)));
typedef float  f32x4  __attribute__((ext_vector_type(4)));

__device__ __forceinline__ unsigned short f2bf(float f) {
  unsigned int u = __float_as_uint(f);
  u += 0x7fff + ((u >> 16) & 1);   // RNE
  return (unsigned short)(u >> 16);
}
__device__ __forceinline__ float sigmoid_f(float x) {
  return 1.0f / (1.0f + __expf(-x));
}
__device__ __forceinline__ float tanh_f(float x) {
  return 1.0f - 2.0f / (__expf(2.0f * x) + 1.0f);
}
__device__ __forceinline__ void gload_lds16(const void* g, void* l) {
  __builtin_amdgcn_global_load_lds(
      (const __attribute__((address_space(1))) void*)g,
      (__attribute__((address_space(3))) void*)l, 16, 0, 0);
}

// gate-interleaved weight column index
__device__ __forceinline__ int cimap(int g, int n) {
  return ((n >> 6) << 8) | ((g >> 1) << 7) | (((n >> 4) & 3) << 5) |
         ((g & 1) << 4) | (n & 15);
}

// ---------------- kernel 1: pack xh = concat(x, out_tm1) as bf16 ------------
__global__ void pack_xh_kernel(const float* __restrict__ x,
                               const float* __restrict__ h,
                               unsigned short* __restrict__ xh) {
  const long total = (long)B_DIM * KDIM / 4;
  for (long i = (long)blockIdx.x * blockDim.x + threadIdx.x; i < total;
       i += (long)gridDim.x * blockDim.x) {
    long e = i * 4;
    int b = (int)(e >> 11);
    int c = (int)(e & 2047);
    float4 v = (c < 1024)
        ? *reinterpret_cast<const float4*>(x + (long)b * 1024 + c)
        : *reinterpret_cast<const float4*>(h + (long)b * 1024 + (c - 1024));
    ushort4 o;
    o.x = f2bf(v.x); o.y = f2bf(v.y); o.z = f2bf(v.z); o.w = f2bf(v.w);
    *reinterpret_cast<ushort4*>(xh + e) = o;
  }
}

// ------- kernel 2: wt[ci][k] = bf16(W_g[k][n]), ci = gate-interleaved -------
__global__ void transpose_w_kernel(const float* __restrict__ Wf,
                                   const float* __restrict__ Wi,
                                   const float* __restrict__ Wc,
                                   const float* __restrict__ Wo,
                                   unsigned short* __restrict__ wt) {
  __shared__ float tile[32][33];
  const int g = blockIdx.z;
  const float* W = (g == 0) ? Wf : (g == 1) ? Wi : (g == 2) ? Wc : Wo;
  const int n0 = blockIdx.x * 32;
  const int k0 = blockIdx.y * 32;
  const int tx = threadIdx.x, ty = threadIdx.y;
#pragma unroll
  for (int r = ty; r < 32; r += 8)
    tile[r][tx] = W[(long)(k0 + r) * NOUT + n0 + tx];
  __syncthreads();
#pragma unroll
  for (int r = ty; r < 32; r += 8) {
    int ci = cimap(g, n0 + r);
    wt[(long)ci * KDIM + k0 + tx] = f2bf(tile[tx][r]);
  }
}

// ------------- kernel 3: 256x256x64 8-phase GEMM + fused LSTM epilogue -----
// LDS map (bytes): A(buf,half) = buf*32768 + half*16384
//                  B(buf,half) = 65536 + buf*32768 + half*16384
#define BAR()   { __builtin_amdgcn_s_barrier(); __builtin_amdgcn_sched_barrier(0); }
#define LGKM0() asm volatile("s_waitcnt lgkmcnt(0)" ::: "memory")
#define VM4()   asm volatile("s_waitcnt vmcnt(4)" ::: "memory")
#define VM0()   asm volatile("s_waitcnt vmcnt(0)" ::: "memory")

__device__ __forceinline__ void stage_half(const char* g, long grow0, int kt,
                                           char* ldsm, int base,
                                           int wave, int lane) {
  const int rsub = lane >> 3;                       // row&7 within 8-row group
  const int scol = (((lane & 7) ^ rsub) << 4);      // pre-swizzled source col
  const long rowb = (grow0 + wave * 8 + rsub) * 4096 + (long)kt * 128 + scol;
  gload_lds16(g + rowb,               ldsm + base + wave * 1024);
  gload_lds16(g + rowb + 64L * 4096,  ldsm + base + 8192 + wave * 1024);
}

#define LOAD_A(BUF, MQ)                                                     \
  _Pragma("unroll") for (int mi = 0; mi < 4; ++mi) {                        \
    const char* p_ = lds + (BUF)*32768 + (MQ)*16384 +                       \
                     (wm * 64 + mi * 16 + lrow) * 128;                      \
    af[mi][0] = *reinterpret_cast<const bf16x8*>(p_ + colA0);               \
    af[mi][1] = *reinterpret_cast<const bf16x8*>(p_ + colA1);               \
  }

#define LOAD_B(BUF, NQ)                                                     \
  _Pragma("unroll") for (int ni = 0; ni < 2; ++ni) {                        \
    const char* p_ = lds + 65536 + (BUF)*32768 + (NQ)*16384 +               \
                     (wn * 32 + ni * 16 + lrow) * 128;                      \
    bq[ni][0] = *reinterpret_cast<const bf16x8*>(p_ + colA0);               \
    bq[ni][1] = *reinterpret_cast<const bf16x8*>(p_ + colA1);               \
  }

#define MFMA16(MQ, NQ)                                                     \
  __builtin_amdgcn_s_setprio(1);                                            \
  _Pragma("unroll") for (int mi = 0; mi < 4; ++mi)                          \
  _Pragma("unroll") for (int ni = 0; ni < 2; ++ni)                          \
  _Pragma("unroll") for (int s = 0; s < 2; ++s)                             \
    acc[MQ][NQ][mi][ni] = __builtin_amdgcn_mfma_f32_16x16x32_bf16(          \
        af[mi][s], bq[ni][s], acc[MQ][NQ][mi][ni], 0, 0, 0);                \
  __builtin_amdgcn_s_setprio(0);

__global__ __launch_bounds__(512, 2)
void lstm_gemm_kernel(const unsigned short* __restrict__ xh,
                      const unsigned short* __restrict__ wt,
                      const float* __restrict__ state,
                      const float* __restrict__ bfp,
                      const float* __restrict__ bip,
                      const float* __restrict__ bcp,
                      const float* __restrict__ bop,
                      float* __restrict__ out) {
  __shared__ __attribute__((aligned(128))) char lds[131072];

  const int tid  = threadIdx.x;
  const int wave = tid >> 6;
  const int lane = tid & 63;
  const int wm = wave >> 2;     // 0..1
  const int wn = wave & 3;      // 0..3

  // XCD-aware swizzle (nwg = 512, divisible by 8)
  int wg = blockIdx.y * 16 + blockIdx.x;
  wg = (wg & 7) * 64 + (wg >> 3);
  const int  bm = wg >> 4;      // 0..31
  const int  bn = wg & 15;      // 0..15
  const long m0 = (long)bm * 256;
  const long n0 = (long)bn * 256;

  const int lrow  = lane & 15;
  const int csw   = (lane & 7) << 4;
  const int ck    = (lane >> 4) << 4;
  const int colA0 = ck ^ csw;          // k-chunk byte col, s=0 (swizzled)
  const int colA1 = (64 | ck) ^ csw;   // s=1

  const char* xh_b = (const char*)xh;  // 4096 B rows
  const char* wt_b = (const char*)wt;  // 4096 B rows

  // ---- prologue: tile0 all 4 halves, then A0(1), B1(1)
  stage_half(xh_b, m0,        0, lds, 0,             wave, lane);  // A0(0)
  stage_half(xh_b, m0 + 128,  0, lds, 16384,         wave, lane);  // A1(0)
  stage_half(wt_b, n0,        0, lds, 65536,         wave, lane);  // B0(0)
  stage_half(wt_b, n0 + 128,  0, lds, 65536 + 16384, wave, lane);  // B1(0)
  stage_half(xh_b, m0,        1, lds, 32768,         wave, lane);  // A0(1)
  stage_half(wt_b, n0 + 128,  1, lds, 65536 + 32768 + 16384, wave, lane); // B1(1)

  f32x4 acc[2][2][4][2] = {};
  bf16x8 af[4][2];
  bf16x8 bq[2][2];

  VM4();
  BAR();

  for (int t = 0; t < 32; t += 2) {
    const int k1 = (t + 1 <= 31) ? t + 1 : 31;
    const int k2 = (t + 2 <= 31) ? t + 2 : 31;
    const int k3 = (t + 3 <= 31) ? t + 3 : 31;

    // ================= tile t (buf0) =================
    // P1 (mq0,nq0) | stage A1(t+1) -> buf1
    LOAD_A(0, 0) LOAD_B(0, 0)
    stage_half(xh_b, m0 + 128, k1, lds, 32768 + 16384, wave, lane);
    BAR(); LGKM0(); MFMA16(0, 0) BAR();
    // P2 (mq0,nq1) | stage B0(t+1) -> buf1
    LOAD_B(0, 1)
    stage_half(wt_b, n0, k1, lds, 65536 + 32768, wave, lane);
    BAR(); LGKM0(); MFMA16(0, 1) BAR();
    // P3 (mq1,nq1) | stage A0(t+2) -> buf0
    LOAD_A(0, 1)
    stage_half(xh_b, m0, k2, lds, 0, wave, lane);
    BAR(); LGKM0(); MFMA16(1, 1) BAR();
    // P4 (mq1,nq0) | stage B1(t+2) -> buf0 | counted wait
    LOAD_B(0, 0)
    stage_half(wt_b, n0 + 128, k2, lds, 65536 + 16384, wave, lane);
    BAR(); LGKM0(); MFMA16(1, 0) VM4(); BAR();

    // ================= tile t+1 (buf1) =================
    // P1 | stage A1(t+2) -> buf0
    LOAD_A(1, 0) LOAD_B(1, 0)
    stage_half(xh_b, m0 + 128, k2, lds, 16384, wave, lane);
    BAR(); LGKM0(); MFMA16(0, 0) BAR();
    // P2 | stage B0(t+2) -> buf0
    LOAD_B(1, 1)
    stage_half(wt_b, n0, k2, lds, 65536, wave, lane);
    BAR(); LGKM0(); MFMA16(0, 1) BAR();
    // P3 | stage A0(t+3) -> buf1
    LOAD_A(1, 1)
    stage_half(xh_b, m0, k3, lds, 32768, wave, lane);
    BAR(); LGKM0(); MFMA16(1, 1) BAR();
    // P4 | stage B1(t+3) -> buf1 | counted wait
    LOAD_B(1, 0)
    stage_half(wt_b, n0 + 128, k3, lds, 65536 + 32768 + 16384, wave, lane);
    BAR(); LGKM0(); MFMA16(1, 0) VM4(); BAR();
  }
  VM0();   // drain before epilogue / endpgm

  // ---- fused LSTM epilogue: lane's 4 n-frags are the 4 gates of column nout
  const int   nout = bn * 64 + wn * 16 + lrow;     // 0..1023
  const int   rsub4 = (lane >> 4) << 2;
  const float bfv = bfp[nout], biv = bip[nout];
  const float bcv = bcp[nout], bov = bop[nout];
  float* out2 = out + (long)B_DIM * NOUT;
#pragma unroll
  for (int mq = 0; mq < 2; ++mq)
#pragma unroll
    for (int mi = 0; mi < 4; ++mi)
#pragma unroll
      for (int v = 0; v < 4; ++v) {
        const long row = m0 + mq * 128 + wm * 64 + mi * 16 + rsub4 + v;
        float fg = sigmoid_f(acc[mq][0][mi][0][v] + bfv);
        float ig = sigmoid_f(acc[mq][0][mi][1][v] + biv);
        float cg = tanh_f   (acc[mq][1][mi][0][v] + bcv);
        float og = sigmoid_f(acc[mq][1][mi][1][v] + bov);
        float st = state[row * NOUT + nout];
        float ns = st * fg + ig * cg;
        out [row * NOUT + nout] = og * tanh_f(ns);
        out2[row * NOUT + nout] = ns;
      }
}

extern "C" void kernel_launch(void* const* d_in, const int* in_sizes, int n_in,
                              void* d_out, int out_size, void* d_ws, size_t ws_size,
                              hipStream_t stream) {
  const float* x     = (const float*)d_in[0];
  const float* h     = (const float*)d_in[1];
  const float* state = (const float*)d_in[2];
  const float* Wf    = (const float*)d_in[3];
  const float* bfp   = (const float*)d_in[4];
  const float* Wi    = (const float*)d_in[5];
  const float* bip   = (const float*)d_in[6];
  const float* Wc    = (const float*)d_in[7];
  const float* bcp   = (const float*)d_in[8];
  const float* Wo    = (const float*)d_in[9];
  const float* bop   = (const float*)d_in[10];
  float* out = (float*)d_out;

  unsigned short* xh = (unsigned short*)d_ws;
  unsigned short* wt = (unsigned short*)((char*)d_ws + (size_t)B_DIM * KDIM * 2);

  hipLaunchKernelGGL(pack_xh_kernel, dim3(2048), dim3(256), 0, stream, x, h, xh);
  hipLaunchKernelGGL(transpose_w_kernel, dim3(NOUT / 32, KDIM / 32, 4),
                     dim3(32, 8), 0, stream, Wf, Wi, Wc, Wo, wt);
  hipLaunchKernelGGL(lstm_gemm_kernel, dim3(16, 32), dim3(512), 0, stream,
                     xh, wt, state, bfp, bip, bcp, bop, out);
}

// Round 4
// 153.267 us; speedup vs baseline: 1.1710x; 1.0318x over previous
//
#include <hip/hip_runtime.h>

#define B_DIM 8192
#define NOUT  1024
#define KDIM  2048

typedef __bf16 bf16x8 __attribute__((ext_vector_type(8)));
typedef float  f32x4  __attribute__((ext_vector_type(4)));

__device__ __forceinline__ unsigned short f2bf(float f) {
  unsigned int u = __float_as_uint(f);
  u += 0x7fff + ((u >> 16) & 1);   // RNE
  return (unsigned short)(u >> 16);
}
__device__ __forceinline__ float sigmoid_f(float x) {
  return 1.0f / (1.0f + __expf(-x));
}
__device__ __forceinline__ float tanh_f(float x) {
  return 1.0f - 2.0f / (__expf(2.0f * x) + 1.0f);
}
__device__ __forceinline__ void gload_lds16(const void* g, void* l) {
  __builtin_amdgcn_global_load_lds(
      (const __attribute__((address_space(1))) void*)g,
      (__attribute__((address_space(3))) void*)l, 16, 0, 0);
}

// gate-interleaved weight column index
__device__ __forceinline__ int cimap(int g, int n) {
  return ((n >> 6) << 8) | ((g >> 1) << 7) | (((n >> 4) & 3) << 5) |
         ((g & 1) << 4) | (n & 15);
}

// ---------------- kernel 1: pack xh = concat(x, out_tm1) as bf16 ------------
__global__ void pack_xh_kernel(const float* __restrict__ x,
                               const float* __restrict__ h,
                               unsigned short* __restrict__ xh) {
  const long total = (long)B_DIM * KDIM / 4;
  for (long i = (long)blockIdx.x * blockDim.x + threadIdx.x; i < total;
       i += (long)gridDim.x * blockDim.x) {
    long e = i * 4;
    int b = (int)(e >> 11);
    int c = (int)(e & 2047);
    float4 v = (c < 1024)
        ? *reinterpret_cast<const float4*>(x + (long)b * 1024 + c)
        : *reinterpret_cast<const float4*>(h + (long)b * 1024 + (c - 1024));
    ushort4 o;
    o.x = f2bf(v.x); o.y = f2bf(v.y); o.z = f2bf(v.z); o.w = f2bf(v.w);
    *reinterpret_cast<ushort4*>(xh + e) = o;
  }
}

// ------- kernel 2: wt[ci][k] = bf16(W_g[k][n]), ci = gate-interleaved -------
__global__ void transpose_w_kernel(const float* __restrict__ Wf,
                                   const float* __restrict__ Wi,
                                   const float* __restrict__ Wc,
                                   const float* __restrict__ Wo,
                                   unsigned short* __restrict__ wt) {
  __shared__ float tile[32][33];
  const int g = blockIdx.z;
  const float* W = (g == 0) ? Wf : (g == 1) ? Wi : (g == 2) ? Wc : Wo;
  const int n0 = blockIdx.x * 32;
  const int k0 = blockIdx.y * 32;
  const int tx = threadIdx.x, ty = threadIdx.y;
#pragma unroll
  for (int r = ty; r < 32; r += 8)
    tile[r][tx] = W[(long)(k0 + r) * NOUT + n0 + tx];
  __syncthreads();
#pragma unroll
  for (int r = ty; r < 32; r += 8) {
    int ci = cimap(g, n0 + r);
    wt[(long)ci * KDIM + k0 + tx] = f2bf(tile[tx][r]);
  }
}

// ------------- kernel 3: 256x256x64 GEMM, 1-barrier phases + fused LSTM ----
// LDS map (bytes): A(buf,half) = buf*32768 + half*16384
//                  B(buf,nq)   = 65536 + buf*32768 + nq*16384
//
// Per-phase body: { ds_reads(p) ; stage 1 half ; vmcnt(6) ; s_barrier ;
//                   (compiler lgkm) ; setprio ; 16 MFMA ; setprio }
// Pipeline: stage(m) complete by end of phase m+3 (vmcnt(6), 2 loads/phase,
// in-order vmcnt); earliest read of stage(m)'s data is phase m+4. WAR: every
// LDS half has >=2 barriers between last-read-completion (lgkmcnt before that
// phase's MFMA, i.e. before next barrier arrival) and its overwrite stage.
#define BAR()   { __builtin_amdgcn_s_barrier(); __builtin_amdgcn_sched_barrier(0); }
#define VM6()   { asm volatile("s_waitcnt vmcnt(6)" ::: "memory"); }
#define VM4()   { asm volatile("s_waitcnt vmcnt(4)" ::: "memory"); }
#define VM0()   { asm volatile("s_waitcnt vmcnt(0)" ::: "memory"); }

__device__ __forceinline__ void stage_half(const char* g, long grow0, int kt,
                                           char* ldsm, int base,
                                           int wave, int lane) {
  const int rsub = lane >> 3;
  const int scol = (((lane & 7) ^ rsub) << 4);      // pre-swizzled source col
  const long rowb = (grow0 + wave * 8 + rsub) * 4096 + (long)kt * 128 + scol;
  gload_lds16(g + rowb,               ldsm + base + wave * 1024);
  gload_lds16(g + rowb + 64L * 4096,  ldsm + base + 8192 + wave * 1024);
}

// NOTE: s=1 column is colA1 = (64|ck)^csw = colA0 ^ 64  (XOR, not +64!) --
// separate base pointers per k-half keep phase offsets compile-time.
#define LOAD_AF(BUF, MQ)                                                    \
  _Pragma("unroll") for (int mi = 0; mi < 4; ++mi) {                        \
    af[mi][0] = *reinterpret_cast<const bf16x8*>(                           \
        baseA0 + (BUF)*32768 + (MQ)*16384 + mi*2048);                       \
    af[mi][1] = *reinterpret_cast<const bf16x8*>(                           \
        baseA1 + (BUF)*32768 + (MQ)*16384 + mi*2048);                       \
  }

#define LOAD_BQ(BUF, NQ, DST)                                               \
  _Pragma("unroll") for (int ni = 0; ni < 2; ++ni) {                        \
    DST[ni][0] = *reinterpret_cast<const bf16x8*>(                          \
        baseB0 + (BUF)*32768 + (NQ)*16384 + ni*2048);                       \
    DST[ni][1] = *reinterpret_cast<const bf16x8*>(                          \
        baseB1 + (BUF)*32768 + (NQ)*16384 + ni*2048);                       \
  }

#define MFMA16(MQ, NQ, BQ)                                                  \
  __builtin_amdgcn_s_setprio(1);                                            \
  _Pragma("unroll") for (int mi = 0; mi < 4; ++mi)                          \
  _Pragma("unroll") for (int ni = 0; ni < 2; ++ni)                          \
  _Pragma("unroll") for (int s = 0; s < 2; ++s)                             \
    acc[MQ][NQ][mi][ni] = __builtin_amdgcn_mfma_f32_16x16x32_bf16(          \
        af[mi][s], BQ[ni][s], acc[MQ][NQ][mi][ni], 0, 0, 0);                \
  __builtin_amdgcn_s_setprio(0);

__global__ __launch_bounds__(512, 2)
void lstm_gemm_kernel(const unsigned short* __restrict__ xh,
                      const unsigned short* __restrict__ wt,
                      const float* __restrict__ state,
                      const float* __restrict__ bfp,
                      const float* __restrict__ bip,
                      const float* __restrict__ bcp,
                      const float* __restrict__ bop,
                      float* __restrict__ out) {
  __shared__ __attribute__((aligned(128))) char lds[131072];

  const int tid  = threadIdx.x;
  const int wave = tid >> 6;
  const int lane = tid & 63;
  const int wm = wave >> 2;     // 0..1
  const int wn = wave & 3;      // 0..3

  // XCD-aware swizzle (nwg = 512, divisible by 8)
  int wg = blockIdx.y * 16 + blockIdx.x;
  wg = (wg & 7) * 64 + (wg >> 3);
  const int  bm = wg >> 4;      // 0..31
  const int  bn = wg & 15;      // 0..15
  const long m0 = (long)bm * 256;
  const long n0 = (long)bn * 256;

  const int lrow  = lane & 15;
  const int csw   = (lane & 7) << 4;
  const int ck    = (lane >> 4) << 4;
  const int colA0 = ck ^ csw;           // swizzled byte col, k-half s=0
  const int colA1 = (64 | ck) ^ csw;    // swizzled byte col, k-half s=1

  const char* baseA0 = lds + (wm * 64 + lrow) * 128 + colA0;
  const char* baseA1 = lds + (wm * 64 + lrow) * 128 + colA1;
  const char* baseB0 = lds + 65536 + (wn * 32 + lrow) * 128 + colA0;
  const char* baseB1 = lds + 65536 + (wn * 32 + lrow) * 128 + colA1;

  const char* xh_b = (const char*)xh;  // 4096 B rows
  const char* wt_b = (const char*)wt;  // 4096 B rows

  // ---- prologue: stage A0(0),B0(0),B1(0),A1(0),A0(1),B0(1); vmcnt(4); bar
  stage_half(xh_b, m0,        0, lds, 0,                     wave, lane); // A0(0)
  stage_half(wt_b, n0,        0, lds, 65536,                 wave, lane); // B0(0)
  stage_half(wt_b, n0 + 128,  0, lds, 65536 + 16384,         wave, lane); // B1(0)
  stage_half(xh_b, m0 + 128,  0, lds, 16384,                 wave, lane); // A1(0)
  stage_half(xh_b, m0,        1, lds, 32768,                 wave, lane); // A0(1)
  stage_half(wt_b, n0,        1, lds, 65536 + 32768,         wave, lane); // B0(1)

  f32x4 acc[2][2][4][2] = {};
  bf16x8 af[4][2];
  bf16x8 bq0[2][2];
  bf16x8 bq1[2][2];

  VM4();
  BAR();

  for (int t = 0; t < 32; t += 2) {
    const int k2c = (t + 2 > 31) ? 31 : t + 2;   // clamped (re-stages same data)
    const int k3c = (t + 3 > 31) ? 31 : t + 3;

    // ================= tile t (buf0) =================
    // P1 (mq0,nq0): read af(A0),bq0(B0) | stage B1(t+1)->buf1
    LOAD_AF(0, 0) LOAD_BQ(0, 0, bq0)
    stage_half(wt_b, n0 + 128, t + 1, lds, 65536 + 32768 + 16384, wave, lane);
    VM6(); BAR();
    MFMA16(0, 0, bq0)
    // P2 (mq0,nq1): read bq1(B1) | stage A1(t+1)->buf1
    LOAD_BQ(0, 1, bq1)
    stage_half(xh_b, m0 + 128, t + 1, lds, 32768 + 16384, wave, lane);
    VM6(); BAR();
    MFMA16(0, 1, bq1)
    // P3 (mq1,nq1): read af(A1) | stage A0(t+2)->buf0
    LOAD_AF(0, 1)
    stage_half(xh_b, m0, k2c, lds, 0, wave, lane);
    VM6(); BAR();
    MFMA16(1, 1, bq1)
    // P4 (mq1,nq0): no reads | stage B0(t+2)->buf0
    stage_half(wt_b, n0, k2c, lds, 65536, wave, lane);
    VM6(); BAR();
    MFMA16(1, 0, bq0)

    // ================= tile t+1 (buf1) =================
    // P1: read af(A0),bq0(B0) | stage B1(t+2)->buf0
    LOAD_AF(1, 0) LOAD_BQ(1, 0, bq0)
    stage_half(wt_b, n0 + 128, k2c, lds, 65536 + 16384, wave, lane);
    VM6(); BAR();
    MFMA16(0, 0, bq0)
    // P2: read bq1(B1) | stage A1(t+2)->buf0
    LOAD_BQ(1, 1, bq1)
    stage_half(xh_b, m0 + 128, k2c, lds, 16384, wave, lane);
    VM6(); BAR();
    MFMA16(0, 1, bq1)
    // P3: read af(A1) | stage A0(t+3)->buf1
    LOAD_AF(1, 1)
    stage_half(xh_b, m0, k3c, lds, 32768, wave, lane);
    VM6(); BAR();
    MFMA16(1, 1, bq1)
    // P4: no reads | stage B0(t+3)->buf1
    stage_half(wt_b, n0, k3c, lds, 65536 + 32768, wave, lane);
    VM6(); BAR();
    MFMA16(1, 0, bq0)
  }
  VM0();   // drain outstanding stages before epilogue

  // ---- fused LSTM epilogue: lane's 4 n-frags are the 4 gates of column nout
  const int   nout = bn * 64 + wn * 16 + lrow;     // 0..1023
  const int   rsub4 = (lane >> 4) << 2;
  const float bfv = bfp[nout], biv = bip[nout];
  const float bcv = bcp[nout], bov = bop[nout];
  float* out2 = out + (long)B_DIM * NOUT;
#pragma unroll
  for (int mq = 0; mq < 2; ++mq)
#pragma unroll
    for (int mi = 0; mi < 4; ++mi)
#pragma unroll
      for (int v = 0; v < 4; ++v) {
        const long row = m0 + mq * 128 + wm * 64 + mi * 16 + rsub4 + v;
        float fg = sigmoid_f(acc[mq][0][mi][0][v] + bfv);
        float ig = sigmoid_f(acc[mq][0][mi][1][v] + biv);
        float cg = tanh_f   (acc[mq][1][mi][0][v] + bcv);
        float og = sigmoid_f(acc[mq][1][mi][1][v] + bov);
        float st = state[row * NOUT + nout];
        float ns = st * fg + ig * cg;
        out [row * NOUT + nout] = og * tanh_f(ns);
        out2[row * NOUT + nout] = ns;
      }
}

extern "C" void kernel_launch(void* const* d_in, const int* in_sizes, int n_in,
                              void* d_out, int out_size, void* d_ws, size_t ws_size,
                              hipStream_t stream) {
  const float* x     = (const float*)d_in[0];
  const float* h     = (const float*)d_in[1];
  const float* state = (const float*)d_in[2];
  const float* Wf    = (const float*)d_in[3];
  const float* bfp   = (const float*)d_in[4];
  const float* Wi    = (const float*)d_in[5];
  const float* bip   = (const float*)d_in[6];
  const float* Wc    = (const float*)d_in[7];
  const float* bcp   = (const float*)d_in[8];
  const float* Wo    = (const float*)d_in[9];
  const float* bop   = (const float*)d_in[10];
  float* out = (float*)d_out;

  unsigned short* xh = (unsigned short*)d_ws;
  unsigned short* wt = (unsigned short*)((char*)d_ws + (size_t)B_DIM * KDIM * 2);

  hipLaunchKernelGGL(pack_xh_kernel, dim3(2048), dim3(256), 0, stream, x, h, xh);
  hipLaunchKernelGGL(transpose_w_kernel, dim3(NOUT / 32, KDIM / 32, 4),
                     dim3(32, 8), 0, stream, Wf, Wi, Wc, Wo, wt);
  hipLaunchKernelGGL(lstm_gemm_kernel, dim3(16, 32), dim3(512), 0, stream,
                     xh, wt, state, bfp, bip, bcp, bop, out);
}

// Round 6
// 153.067 us; speedup vs baseline: 1.1725x; 1.0013x over previous
//
#include <hip/hip_runtime.h>

#define B_DIM 8192
#define NOUT  1024
#define KDIM  2048

typedef __bf16 bf16x8 __attribute__((ext_vector_type(8)));
typedef float  f32x4  __attribute__((ext_vector_type(4)));

__device__ __forceinline__ unsigned short f2bf(float f) {
  unsigned int u = __float_as_uint(f);
  u += 0x7fff + ((u >> 16) & 1);   // RNE
  return (unsigned short)(u >> 16);
}
__device__ __forceinline__ float sigmoid_f(float x) {
  return 1.0f / (1.0f + __expf(-x));
}
__device__ __forceinline__ float tanh_f(float x) {
  return 1.0f - 2.0f / (__expf(2.0f * x) + 1.0f);
}
__device__ __forceinline__ void gload_lds16(const void* g, void* l) {
  __builtin_amdgcn_global_load_lds(
      (const __attribute__((address_space(1))) void*)g,
      (__attribute__((address_space(3))) void*)l, 16, 0, 0);
}

// gate-interleaved weight column index (round-2/4 mapping)
__device__ __forceinline__ int cimap(int g, int n) {
  return ((n >> 6) << 8) | ((g >> 1) << 7) | (((n >> 4) & 3) << 5) |
         ((g & 1) << 4) | (n & 15);
}

// ---------------- kernel 1: pack xh = concat(x, out_tm1) as bf16 ------------
__global__ void pack_xh_kernel(const float* __restrict__ x,
                               const float* __restrict__ h,
                               unsigned short* __restrict__ xh) {
  const long total = (long)B_DIM * KDIM / 4;
  for (long i = (long)blockIdx.x * blockDim.x + threadIdx.x; i < total;
       i += (long)gridDim.x * blockDim.x) {
    long e = i * 4;
    int b = (int)(e >> 11);
    int c = (int)(e & 2047);
    float4 v = (c < 1024)
        ? *reinterpret_cast<const float4*>(x + (long)b * 1024 + c)
        : *reinterpret_cast<const float4*>(h + (long)b * 1024 + (c - 1024));
    ushort4 o;
    o.x = f2bf(v.x); o.y = f2bf(v.y); o.z = f2bf(v.z); o.w = f2bf(v.w);
    *reinterpret_cast<ushort4*>(xh + e) = o;
  }
}

// ------- kernel 2: wt[ci][k] = bf16(W_g[k][n]), ci = gate-interleaved -------
__global__ void transpose_w_kernel(const float* __restrict__ Wf,
                                   const float* __restrict__ Wi,
                                   const float* __restrict__ Wc,
                                   const float* __restrict__ Wo,
                                   unsigned short* __restrict__ wt) {
  __shared__ float tile[32][33];
  const int g = blockIdx.z;
  const float* W = (g == 0) ? Wf : (g == 1) ? Wi : (g == 2) ? Wc : Wo;
  const int n0 = blockIdx.x * 32;
  const int k0 = blockIdx.y * 32;
  const int tx = threadIdx.x, ty = threadIdx.y;
#pragma unroll
  for (int r = ty; r < 32; r += 8)
    tile[r][tx] = W[(long)(k0 + r) * NOUT + n0 + tx];
  __syncthreads();
#pragma unroll
  for (int r = ty; r < 32; r += 8) {
    int ci = cimap(g, n0 + r);
    wt[(long)ci * KDIM + k0 + tx] = f2bf(tile[tx][r]);
  }
}

// ---- kernel 3: 256x256x64 GEMM, 2 phases/tile, pure dbuf + fused LSTM -----
// LDS map (bytes): A(buf,half) = buf*32768 + half*16384
//                  B(buf,half) = 65536 + buf*32768 + half*16384
// Phase A body: { stage {A0,B0,B1}(t+1)->buf^1 (6 loads); read A0,B0,B1(buf);
//                 vmcnt(6); BAR; 32 MFMA (quadrants (0,0),(0,1)) }
// Phase B body: { stage {A1}(t+1)->buf^1 (2 loads); read A1(buf);
//                 vmcnt(2); BAR; 32 MFMA (quadrants (1,1),(1,0)) }
// RAW: vmcnt(6)@A retires prev B-stage (A1(t), read this phase-B);
//      vmcnt(2)@B retires this A-stage ({A0,B0,B1}(t+1), read next phase-A);
//      both are covered by the barrier that follows the wait.
// WAR: stages always write buf^1 while reads are from buf; buf^1's regions
//      were last read one full tile earlier, and every stage issues after a
//      barrier that program-order-follows all waves' consuming MFMAs.
#define BAR()   { __builtin_amdgcn_s_barrier(); __builtin_amdgcn_sched_barrier(0); }
#define VM6()   { asm volatile("s_waitcnt vmcnt(6)" ::: "memory"); }
#define VM2()   { asm volatile("s_waitcnt vmcnt(2)" ::: "memory"); }
#define VM0()   { asm volatile("s_waitcnt vmcnt(0)" ::: "memory"); }

__device__ __forceinline__ void stage_half(const char* g, long grow0, int kt,
                                           char* ldsm, int base,
                                           int wave, int lane) {
  const int rsub = lane >> 3;
  const int scol = (((lane & 7) ^ rsub) << 4);      // pre-swizzled source col
  const long rowb = (grow0 + wave * 8 + rsub) * 4096 + (long)kt * 128 + scol;
  gload_lds16(g + rowb,               ldsm + base + wave * 1024);
  gload_lds16(g + rowb + 64L * 4096,  ldsm + base + 8192 + wave * 1024);
}

// s=1 column is colA1 = (64|ck)^csw = colA0 ^ 64 (XOR!) -- separate bases.
#define LOAD_AF(BUF, MQ)                                                    \
  _Pragma("unroll") for (int mi = 0; mi < 4; ++mi) {                        \
    af[mi][0] = *reinterpret_cast<const bf16x8*>(                           \
        baseA0 + (BUF)*32768 + (MQ)*16384 + mi*2048);                       \
    af[mi][1] = *reinterpret_cast<const bf16x8*>(                           \
        baseA1 + (BUF)*32768 + (MQ)*16384 + mi*2048);                       \
  }

#define LOAD_BQ(BUF, NQ, DST)                                               \
  _Pragma("unroll") for (int ni = 0; ni < 2; ++ni) {                        \
    DST[ni][0] = *reinterpret_cast<const bf16x8*>(                          \
        baseB0 + (BUF)*32768 + (NQ)*16384 + ni*2048);                       \
    DST[ni][1] = *reinterpret_cast<const bf16x8*>(                          \
        baseB1 + (BUF)*32768 + (NQ)*16384 + ni*2048);                       \
  }

#define MFMA16(MQ, NQ, BQ)                                                  \
  _Pragma("unroll") for (int mi = 0; mi < 4; ++mi)                          \
  _Pragma("unroll") for (int ni = 0; ni < 2; ++ni)                          \
  _Pragma("unroll") for (int s = 0; s < 2; ++s)                             \
    acc[MQ][NQ][mi][ni] = __builtin_amdgcn_mfma_f32_16x16x32_bf16(          \
        af[mi][s], BQ[ni][s], acc[MQ][NQ][mi][ni], 0, 0, 0);

__global__ __launch_bounds__(512, 2)
void lstm_gemm_kernel(const unsigned short* __restrict__ xh,
                      const unsigned short* __restrict__ wt,
                      const float* __restrict__ state,
                      const float* __restrict__ bfp,
                      const float* __restrict__ bip,
                      const float* __restrict__ bcp,
                      const float* __restrict__ bop,
                      float* __restrict__ out) {
  __shared__ __attribute__((aligned(128))) char lds[131072];

  const int tid  = threadIdx.x;
  const int wave = tid >> 6;
  const int lane = tid & 63;
  const int wm = wave >> 2;     // 0..1
  const int wn = wave & 3;      // 0..3

  // XCD-aware swizzle (nwg = 512, divisible by 8)
  int wg = blockIdx.y * 16 + blockIdx.x;
  wg = (wg & 7) * 64 + (wg >> 3);
  const int  bm = wg >> 4;      // 0..31
  const int  bn = wg & 15;      // 0..15
  const long m0 = (long)bm * 256;
  const long n0 = (long)bn * 256;

  const int lrow  = lane & 15;
  const int csw   = (lane & 7) << 4;
  const int ck    = (lane >> 4) << 4;
  const int colA0 = ck ^ csw;           // swizzled byte col, k-half s=0
  const int colA1 = (64 | ck) ^ csw;    // swizzled byte col, k-half s=1

  const char* baseA0 = lds + (wm * 64 + lrow) * 128 + colA0;
  const char* baseA1 = lds + (wm * 64 + lrow) * 128 + colA1;
  const char* baseB0 = lds + 65536 + (wn * 32 + lrow) * 128 + colA0;
  const char* baseB1 = lds + 65536 + (wn * 32 + lrow) * 128 + colA1;

  const char* xh_b = (const char*)xh;  // 4096 B rows
  const char* wt_b = (const char*)wt;  // 4096 B rows

  // ---- prologue: stage all 4 halves of tile 0 into buf0; drain; barrier
  stage_half(xh_b, m0,        0, lds, 0,             wave, lane); // A0(0)
  stage_half(wt_b, n0,        0, lds, 65536,         wave, lane); // B0(0)
  stage_half(wt_b, n0 + 128,  0, lds, 65536 + 16384, wave, lane); // B1(0)
  stage_half(xh_b, m0 + 128,  0, lds, 16384,         wave, lane); // A1(0)

  f32x4 acc[2][2][4][2] = {};
  bf16x8 af[4][2];
  bf16x8 bq0[2][2];
  bf16x8 bq1[2][2];

  VM0();
  BAR();

  for (int t = 0; t < 32; t += 2) {
    const int k1  = t + 1;
    const int k2c = (t + 2 > 31) ? 31 : t + 2;   // clamp: re-stage, unread

    // ================= tile t (buf0), stage (t+1)->buf1 =================
    // Phase A
    stage_half(xh_b, m0,       k1, lds, 32768,         wave, lane); // A0->buf1
    stage_half(wt_b, n0,       k1, lds, 65536 + 32768, wave, lane); // B0->buf1
    stage_half(wt_b, n0 + 128, k1, lds, 65536 + 32768 + 16384, wave, lane);
    LOAD_AF(0, 0) LOAD_BQ(0, 0, bq0) LOAD_BQ(0, 1, bq1)
    VM6(); BAR();
    __builtin_amdgcn_s_setprio(1);
    MFMA16(0, 0, bq0) MFMA16(0, 1, bq1)
    __builtin_amdgcn_s_setprio(0);
    // Phase B
    stage_half(xh_b, m0 + 128, k1, lds, 32768 + 16384, wave, lane); // A1->buf1
    LOAD_AF(0, 1)
    VM2(); BAR();
    __builtin_amdgcn_s_setprio(1);
    MFMA16(1, 1, bq1) MFMA16(1, 0, bq0)
    __builtin_amdgcn_s_setprio(0);

    // ================= tile t+1 (buf1), stage (t+2)->buf0 =================
    // Phase A
    stage_half(xh_b, m0,       k2c, lds, 0,             wave, lane); // A0->buf0
    stage_half(wt_b, n0,       k2c, lds, 65536,         wave, lane); // B0->buf0
    stage_half(wt_b, n0 + 128, k2c, lds, 65536 + 16384, wave, lane);
    LOAD_AF(1, 0) LOAD_BQ(1, 0, bq0) LOAD_BQ(1, 1, bq1)
    VM6(); BAR();
    __builtin_amdgcn_s_setprio(1);
    MFMA16(0, 0, bq0) MFMA16(0, 1, bq1)
    __builtin_amdgcn_s_setprio(0);
    // Phase B
    stage_half(xh_b, m0 + 128, k2c, lds, 16384, wave, lane);        // A1->buf0
    LOAD_AF(1, 1)
    VM2(); BAR();
    __builtin_amdgcn_s_setprio(1);
    MFMA16(1, 1, bq1) MFMA16(1, 0, bq0)
    __builtin_amdgcn_s_setprio(0);
  }
  VM0();   // drain outstanding stages before epilogue

  // ---- fused LSTM epilogue: lane's 4 n-frags are the 4 gates of column nout
  const int   nout = bn * 64 + wn * 16 + lrow;     // 0..1023
  const int   rsub4 = (lane >> 4) << 2;
  const float bfv = bfp[nout], biv = bip[nout];
  const float bcv = bcp[nout], bov = bop[nout];
  float* out2 = out + (long)B_DIM * NOUT;
#pragma unroll
  for (int mq = 0; mq < 2; ++mq)
#pragma unroll
    for (int mi = 0; mi < 4; ++mi)
#pragma unroll
      for (int v = 0; v < 4; ++v) {
        const long row = m0 + mq * 128 + wm * 64 + mi * 16 + rsub4 + v;
        float fg = sigmoid_f(acc[mq][0][mi][0][v] + bfv);
        float ig = sigmoid_f(acc[mq][0][mi][1][v] + biv);
        float cg = tanh_f   (acc[mq][1][mi][0][v] + bcv);
        float og = sigmoid_f(acc[mq][1][mi][1][v] + bov);
        float st = state[row * NOUT + nout];
        float ns = st * fg + ig * cg;
        out [row * NOUT + nout] = og * tanh_f(ns);
        out2[row * NOUT + nout] = ns;
      }
}

extern "C" void kernel_launch(void* const* d_in, const int* in_sizes, int n_in,
                              void* d_out, int out_size, void* d_ws, size_t ws_size,
                              hipStream_t stream) {
  const float* x     = (const float*)d_in[0];
  const float* h     = (const float*)d_in[1];
  const float* state = (const float*)d_in[2];
  const float* Wf    = (const float*)d_in[3];
  const float* bfp   = (const float*)d_in[4];
  const float* Wi    = (const float*)d_in[5];
  const float* bip   = (const float*)d_in[6];
  const float* Wc    = (const float*)d_in[7];
  const float* bcp   = (const float*)d_in[8];
  const float* Wo    = (const float*)d_in[9];
  const float* bop   = (const float*)d_in[10];
  float* out = (float*)d_out;

  unsigned short* xh = (unsigned short*)d_ws;
  unsigned short* wt = (unsigned short*)((char*)d_ws + (size_t)B_DIM * KDIM * 2);

  hipLaunchKernelGGL(pack_xh_kernel, dim3(2048), dim3(256), 0, stream, x, h, xh);
  hipLaunchKernelGGL(transpose_w_kernel, dim3(NOUT / 32, KDIM / 32, 4),
                     dim3(32, 8), 0, stream, Wf, Wi, Wc, Wo, wt);
  hipLaunchKernelGGL(lstm_gemm_kernel, dim3(16, 32), dim3(512), 0, stream,
                     xh, wt, state, bfp, bip, bcp, bop, out);
}